// Round 9
// baseline (402.992 us; speedup 1.0000x reference)
//
#include <hip/hip_runtime.h>
#include <hip/hip_bf16.h>
#include <math.h>

// Problem constants
#define BB 16
#define NN 4096
#define CC 256
#define NC 768     // 3*C
#define MTOT (BB * NN)   // 65536 tokens

typedef __attribute__((ext_vector_type(8))) __bf16 bf16x8;
typedef __attribute__((ext_vector_type(4))) float f32x4;

__device__ __forceinline__ unsigned short f2bf(float f) {
    union { float f; unsigned int u; } v; v.f = f;
    unsigned int r = (v.u + 0x7FFFu + ((v.u >> 16) & 1u)) >> 16;
    return (unsigned short)r;
}
__device__ __forceinline__ float bf2f(unsigned short b) {
    union { unsigned int u; float f; } v; v.u = ((unsigned int)b) << 16;
    return v.f;
}

#define GL16(gp, lp) \
    __builtin_amdgcn_global_load_lds((const __attribute__((address_space(1))) void*)(gp), \
                                     (__attribute__((address_space(3))) void*)(lp), 16, 0, 0)

// ---------------------------------------------------------------------------
// PREP kernel: fuses the old conv_all (f32->bf16 repack) into the weight
// GEMMs.  Tiles are staged f32 -> regs -> bf16 -> LDS per K-iter, so the
// bf16 intermediate arrays (Wqb/Wkb/Wvs/WpT) and one kernel launch vanish.
//   z<3 : MtY_z = scale * Wk_z Wq_z^T  (256x256);  A[m][k]=Wqkv[z][m][256+k],
//         Bt[n][k]=Wqkv[z][n][k]
//   z=3 : PtZ = (1/3) * Wproj^T x Wv   (256x768);  A[m][k]=Wproj[k][m],
//         Bt[n][k]=Wqkv[n/256][n%256][512+k]  (= row n of the (768,768) view)
// Same slot/swizzle layout and epilogue as the old wgemm -> bit-identical
// MtY/PtZ.
// ---------------------------------------------------------------------------
__global__ __launch_bounds__(256) void prep(const float* __restrict__ Wqkv,
                                            const float* __restrict__ Wproj,
                                            unsigned short* __restrict__ MtY,
                                            unsigned short* __restrict__ PtZ) {
    const int z = blockIdx.z;
    if (z < 3 && blockIdx.x >= 2) return;
    const int bm = blockIdx.y * 128, bn = blockIdx.x * 128;
    const int nout = (z < 3) ? CC : NC;
    const float mult = (z < 3) ? 0.0625f : (1.0f / 3.0f);
    unsigned short* C = (z < 3) ? (MtY + (size_t)z * CC * CC) : PtZ;

    __shared__ unsigned short As[128 * 32];
    __shared__ unsigned short Bs[128 * 32];

    const int tid = threadIdx.x;
    const int lane = tid & 63;
    const int wave = tid >> 6;
    const int q = lane >> 4;
    const int r16 = lane & 15;
    const int wm = (wave >> 1) * 64;
    const int wn = (wave & 1) * 64;
    const int sw = (q ^ ((r16 >> 1) & 3)) * 8;

    const int r0 = tid >> 2, kc0 = (tid & 3) ^ ((r0 >> 1) & 3);
    const int e1 = tid + 256, r1 = e1 >> 2, kc1 = ((e1 & 3)) ^ ((r1 >> 1) & 3);

    f32x4 acc[4][4];
#pragma unroll
    for (int i = 0; i < 4; ++i)
#pragma unroll
        for (int j = 0; j < 4; ++j) acc[i][j] = {0.f, 0.f, 0.f, 0.f};

    for (int kt = 0; kt < CC; kt += 32) {
        if (kt) __syncthreads();
        // ---- stage A slots (e0,e1) and B slots (e0,e1): f32 -> bf16 -> LDS
        {
            float v[8];
            unsigned short p8[8];
            // A e0
            if (z < 3) {
                const float* p = Wqkv + (size_t)(z * 256 + bm + r0) * NC + 256 + kt + kc0 * 8;
                float4 a = *(const float4*)p, b = *(const float4*)(p + 4);
                v[0]=a.x; v[1]=a.y; v[2]=a.z; v[3]=a.w; v[4]=b.x; v[5]=b.y; v[6]=b.z; v[7]=b.w;
            } else {
                const float* p = Wproj + (size_t)(kt + kc0 * 8) * CC + bm + r0;
#pragma unroll
                for (int j = 0; j < 8; ++j) v[j] = p[(size_t)j * CC];
            }
#pragma unroll
            for (int j = 0; j < 8; ++j) p8[j] = f2bf(v[j]);
            *(float4*)(As + tid * 8) = *(const float4*)p8;
            // A e1
            if (z < 3) {
                const float* p = Wqkv + (size_t)(z * 256 + bm + r1) * NC + 256 + kt + kc1 * 8;
                float4 a = *(const float4*)p, b = *(const float4*)(p + 4);
                v[0]=a.x; v[1]=a.y; v[2]=a.z; v[3]=a.w; v[4]=b.x; v[5]=b.y; v[6]=b.z; v[7]=b.w;
            } else {
                const float* p = Wproj + (size_t)(kt + kc1 * 8) * CC + bm + r1;
#pragma unroll
                for (int j = 0; j < 8; ++j) v[j] = p[(size_t)j * CC];
            }
#pragma unroll
            for (int j = 0; j < 8; ++j) p8[j] = f2bf(v[j]);
            *(float4*)(As + e1 * 8) = *(const float4*)p8;
            // B e0
            {
                const float* p = (z < 3)
                    ? Wqkv + (size_t)(z * 256 + bn + r0) * NC + kt + kc0 * 8
                    : Wqkv + (size_t)(bn + r0) * NC + 512 + kt + kc0 * 8;
                float4 a = *(const float4*)p, b = *(const float4*)(p + 4);
                p8[0]=f2bf(a.x); p8[1]=f2bf(a.y); p8[2]=f2bf(a.z); p8[3]=f2bf(a.w);
                p8[4]=f2bf(b.x); p8[5]=f2bf(b.y); p8[6]=f2bf(b.z); p8[7]=f2bf(b.w);
                *(float4*)(Bs + tid * 8) = *(const float4*)p8;
            }
            // B e1
            {
                const float* p = (z < 3)
                    ? Wqkv + (size_t)(z * 256 + bn + r1) * NC + kt + kc1 * 8
                    : Wqkv + (size_t)(bn + r1) * NC + 512 + kt + kc1 * 8;
                float4 a = *(const float4*)p, b = *(const float4*)(p + 4);
                p8[0]=f2bf(a.x); p8[1]=f2bf(a.y); p8[2]=f2bf(a.z); p8[3]=f2bf(a.w);
                p8[4]=f2bf(b.x); p8[5]=f2bf(b.y); p8[6]=f2bf(b.z); p8[7]=f2bf(b.w);
                *(float4*)(Bs + e1 * 8) = *(const float4*)p8;
            }
        }
        __syncthreads();

        bf16x8 afv[4], bfv[4];
#pragma unroll
        for (int mi = 0; mi < 4; ++mi)
            afv[mi] = *(const bf16x8*)(As + (wm + mi * 16 + r16) * 32 + sw);
#pragma unroll
        for (int ni = 0; ni < 4; ++ni)
            bfv[ni] = *(const bf16x8*)(Bs + (wn + ni * 16 + r16) * 32 + sw);
#pragma unroll
        for (int mi = 0; mi < 4; ++mi)
#pragma unroll
            for (int ni = 0; ni < 4; ++ni)
                acc[mi][ni] = __builtin_amdgcn_mfma_f32_16x16x32_bf16(
                    afv[mi], bfv[ni], acc[mi][ni], 0, 0, 0);
    }

#pragma unroll
    for (int mi = 0; mi < 4; ++mi)
#pragma unroll
        for (int ni = 0; ni < 4; ++ni) {
            int row0 = bm + wm + mi * 16 + q * 4;
            int col = bn + wn + ni * 16 + r16;
#pragma unroll
            for (int r = 0; r < 4; ++r)
                C[(size_t)(row0 + r) * nout + col] = f2bf(acc[mi][ni][r] * mult);
        }
}

// ---------------------------------------------------------------------------
// MEGA kernel, v5: v4 + M-phase col-split-4 (zero-duplication M weight reads).
//
// M phase: every wave owns ALL 64 tokens (af[4tf][8kt] persistent regs) and a
// PRIVATE 64-col quarter (cols wv*64..+64) -> each staged M byte is ds_read by
// exactly ONE wave (v4: two).  M stage = one 32-k chunk x all 256 cols (16KB,
// quarter gl at +gl*2048 els).  16 MFMA / 4 B-reads per wave per slot.
// Logits: one lump at sl==7 per dilation: wave computes partials for all 64
// tokens over its cols (yseg transpose + 6 MFMA per tf); part[4][64][3]
// summed by all waves at P sl==0.
// P phase: v4 verbatim (2x2 split: tokb=(wv>>1)*32, cg=wv&1); za center uses
// af[((wv>>1)*2+tt)*8+kt].
//
// Stage stream: 48 stages x 16KB ring-2, issue 1 ahead, consume =
// s_waitcnt vmcnt(0) + raw s_barrier (proven v4 discipline).
//
// LDS: xbuf 70x264 (36960) + bstage 2x16KB (32768) + yseg 4x16x66 (8448)
//      + part 4x64x3 f32 (3072) = 81248 B -> still 2 blocks/CU (<=81920).
// ---------------------------------------------------------------------------
__global__ __launch_bounds__(256, 2) void mega(const float* __restrict__ xf,
                                               const unsigned short* __restrict__ MtY,
                                               const unsigned short* __restrict__ PtZ,
                                               const float* __restrict__ bias,
                                               float* __restrict__ out) {
    __shared__ __align__(16) unsigned short xbuf[70 * 264];
    __shared__ __align__(16) unsigned short bstage[2 * 8192];
    __shared__ __align__(16) unsigned short yseg[4 * 16 * 66];
    __shared__ __align__(16) float part[4][64][3];

    const int tid = threadIdx.x;
    const int lane = tid & 63;
    const int wv = tid >> 6;
    const int q = lane >> 4;
    const int r16 = lane & 15;
    const int t0 = blockIdx.x * 64;
    const int tokb = (wv >> 1) * 32;   // P-phase token base
    const int cg = wv & 1;             // P-phase column group

    // staging source precompute (conflict swizzle: slot (tid&3) holds kc)
    const int c2t = tid >> 2;                       // 0..63
    const int kct = (tid & 3) ^ ((tid >> 3) & 3);
    const unsigned short* mB = MtY + (size_t)c2t * CC + kct * 8;
    const unsigned short* pB = PtZ + (size_t)c2t * NC + kct * 8;

    // Stage gs (0..47): dil i2 = gs>>4; r = gs&15.
    //  r<8 : M-stage: k-chunk r (32k) x ALL 256 cols; quarter gl at +gl*2048.
    //  r>=8: P-stage: 256 g x 32 a (kt = r-8); quarter gl at +gl*2048.
    auto issue_stage = [&](int gs) {
        if (gs >= 48) return;
        unsigned short* dst = bstage + (gs & 1) * 8192 + tid * 8;
        const int i2 = gs >> 4;
        const int r = gs & 15;
        if (r < 8) {
            const unsigned short* s0 = mB + (size_t)(i2 * 256) * CC + r * 32;
            GL16(s0, dst);                                  // cols 0..63
            GL16(s0 + (size_t)64 * CC, dst + 2048);         // cols 64..127
            GL16(s0 + (size_t)128 * CC, dst + 4096);        // cols 128..191
            GL16(s0 + (size_t)192 * CC, dst + 6144);        // cols 192..255
        } else {
            const unsigned short* s0 = pB + i2 * 256 + (r - 8) * 32;
            GL16(s0, dst);                                  // g 0..63
            GL16(s0 + (size_t)64 * NC, dst + 2048);         // g 64..127
            GL16(s0 + (size_t)128 * NC, dst + 4096);        // g 128..191
            GL16(s0 + (size_t)192 * NC, dst + 6144);        // g 192..255
        }
    };

    issue_stage(0);   // flies while x is staged

    // ---- stage x rows [t0-3, t0+67) fp32 -> bf16 LDS (clamped; masked later)
    for (int it = 0; it < 9; ++it) {
        int e = it * 256 + tid;          // 70 rows * 32 chunks = 2240
        if (e < 2240) {
            int rr = e >> 5, c = e & 31;
            int gr = t0 - 3 + rr;
            gr = gr < 0 ? 0 : (gr > MTOT - 1 ? MTOT - 1 : gr);
            const float* xp = xf + (size_t)gr * CC + c * 8;
            float4 a = *(const float4*)xp;
            float4 b = *(const float4*)(xp + 4);
            unsigned short p[8];
            p[0] = f2bf(a.x); p[1] = f2bf(a.y); p[2] = f2bf(a.z); p[3] = f2bf(a.w);
            p[4] = f2bf(b.x); p[5] = f2bf(b.y); p[6] = f2bf(b.z); p[7] = f2bf(b.w);
            *(float4*)(xbuf + rr * 264 + c * 8) = *(const float4*)p;
        }
    }
    __syncthreads();   // drains x loads AND stage 0 (one-time vmcnt(0))

    // persistent A-fragments: ALL 64 block tokens x 256 k (4 tf x 8 kt)
    bf16x8 af[32];
#pragma unroll
    for (int tf = 0; tf < 4; ++tf)
#pragma unroll
        for (int kt = 0; kt < 8; ++kt)
            af[tf * 8 + kt] = *(const bf16x8*)(xbuf + (3 + tf * 16 + r16) * 264 +
                                               kt * 32 + q * 8);

    f32x4 oacc[16];   // [tf*8 + ch*4 + cfl]: rows tokb+tf*16+q*4+r, col (ch*2+cg)*64+cfl*16+r16
#pragma unroll
    for (int j = 0; j < 16; ++j) oacc[j] = {0.f, 0.f, 0.f, 0.f};

    const int fragsw = q ^ ((r16 >> 1) & 3);   // fragment k-chunk swizzle

#pragma unroll 1
    for (int i = 0; i < 3; ++i) {
        const int dil = i + 1;
        f32x4 yacc[16];   // [tf*4 + cfl]: Y rows tf*16+q*4+r, col wv*64+cfl*16+r16
#pragma unroll
        for (int j = 0; j < 16; ++j) yacc[j] = {0.f, 0.f, 0.f, 0.f};
        float wgt[2][3];
        union ZA { unsigned int w[4]; bf16x8 v; };
        ZA za[2];

        // ================= M phase: 8 slots (k-chunks) =================
#pragma unroll
        for (int sl = 0; sl < 8; ++sl) {
            asm volatile("s_waitcnt vmcnt(0)" ::: "memory");  // stage ready (this wave)
            __builtin_amdgcn_s_barrier();                     // -> ready block-wide
            __builtin_amdgcn_sched_barrier(0);
            const unsigned short* bp = bstage + (sl & 1) * 8192;
            issue_stage(i * 16 + sl + 1);
            bf16x8 bfr[4];
#pragma unroll
            for (int cfl = 0; cfl < 4; ++cfl)
                bfr[cfl] = *(const bf16x8*)(bp + wv * 2048 +
                               ((cfl * 16 + r16) * 4 + fragsw) * 8);
            __builtin_amdgcn_s_setprio(1);
#pragma unroll
            for (int tf = 0; tf < 4; ++tf)
#pragma unroll
                for (int cfl = 0; cfl < 4; ++cfl)
                    yacc[tf * 4 + cfl] = __builtin_amdgcn_mfma_f32_16x16x32_bf16(
                        af[tf * 8 + sl], bfr[cfl], yacc[tf * 4 + cfl], 0, 0, 0);
            __builtin_amdgcn_s_setprio(0);

            if (sl == 7) {
                // logit lump: partials for all 64 tokens over wave's 64 cols
                unsigned short* ys = yseg + wv * (16 * 66);
#pragma unroll
                for (int tf = 0; tf < 4; ++tf) {
#pragma unroll
                    for (int cfl = 0; cfl < 4; ++cfl)
#pragma unroll
                        for (int rr = 0; rr < 4; ++rr)
                            ys[(q * 4 + rr) * 66 + cfl * 16 + r16] =
                                f2bf(yacc[tf * 4 + cfl][rr]);
                    asm volatile("s_waitcnt lgkmcnt(0)" ::: "memory");
                    __builtin_amdgcn_sched_barrier(0);
                    bf16x8 ya0 = *(const bf16x8*)(ys + r16 * 66 + q * 8);
                    bf16x8 ya1 = *(const bf16x8*)(ys + r16 * 66 + 32 + q * 8);
                    f32x4 lc[3];
#pragma unroll
                    for (int j = 0; j < 3; ++j) lc[j] = {0.f, 0.f, 0.f, 0.f};
#pragma unroll
                    for (int j = 0; j < 3; ++j) {
                        const unsigned short* xr =
                            xbuf + (3 + tf * 16 + r16 + (j - 1) * dil) * 264 +
                            wv * 64 + q * 8;
                        lc[j] = __builtin_amdgcn_mfma_f32_16x16x32_bf16(
                            ya0, *(const bf16x8*)xr, lc[j], 0, 0, 0);
                        lc[j] = __builtin_amdgcn_mfma_f32_16x16x32_bf16(
                            ya1, *(const bf16x8*)(xr + 32), lc[j], 0, 0, 0);
                    }
                    if (q == (r16 >> 2)) {     // diag lanes own token tf*16+r16
                        const int rs = r16 & 3;
#pragma unroll
                        for (int j = 0; j < 3; ++j) {
                            float v = rs == 0 ? lc[j][0] : rs == 1 ? lc[j][1]
                                    : rs == 2 ? lc[j][2] : lc[j][3];
                            part[wv][tf * 16 + r16][j] = v;
                        }
                    }
                }
                asm volatile("s_waitcnt lgkmcnt(0)" ::: "memory");  // publish parts
            }
        }

        // ================= P phase: 8 slots (kt 0..7) =================
#pragma unroll
        for (int sl = 0; sl < 8; ++sl) {
            asm volatile("s_waitcnt vmcnt(0)" ::: "memory");
            __builtin_amdgcn_s_barrier();
            __builtin_amdgcn_sched_barrier(0);
            const unsigned short* bp = bstage + (sl & 1) * 8192;
            issue_stage(i * 16 + 8 + sl + 1);
            if (sl == 0) {
                // combine 4 col-quarter partials + softmax (all lanes)
#pragma unroll
                for (int tt = 0; tt < 2; ++tt) {
                    const int tok = tokb + tt * 16 + r16;
                    float l0 = part[0][tok][0] + part[1][tok][0] +
                               part[2][tok][0] + part[3][tok][0];
                    float l1 = part[0][tok][1] + part[1][tok][1] +
                               part[2][tok][1] + part[3][tok][1];
                    float l2 = part[0][tok][2] + part[1][tok][2] +
                               part[2][tok][2] + part[3][tok][2];
                    const int ns = (t0 + tok) & (NN - 1);
                    const bool vlo = ns >= dil;
                    const bool vhi = ns + dil < NN;
                    l0 = vlo ? l0 : 0.f;    // zero-logit padding (matches reference)
                    l2 = vhi ? l2 : 0.f;
                    float mx = fmaxf(l0, fmaxf(l1, l2));
                    float e0 = __expf(l0 - mx), e1 = __expf(l1 - mx), e2 = __expf(l2 - mx);
                    float inv = 1.0f / (e0 + e1 + e2);
                    wgt[tt][0] = vlo ? e0 * inv : 0.f;
                    wgt[tt][1] = e1 * inv;
                    wgt[tt][2] = vhi ? e2 * inv : 0.f;
                }
            }
            // build z A-frags for this k-chunk (center term from persistent af)
#pragma unroll
            for (int tt = 0; tt < 2; ++tt) {
                const unsigned short* xr1 =
                    xbuf + (3 + tokb + tt * 16 + r16) * 264 + sl * 32 + q * 8;
                bf16x8 a0 = *(const bf16x8*)(xr1 - dil * 264);
                bf16x8 a2 = *(const bf16x8*)(xr1 + dil * 264);
                const unsigned short* u0 = (const unsigned short*)&a0;
                const unsigned short* u1 = (const unsigned short*)&af[((wv >> 1) * 2 + tt) * 8 + sl];
                const unsigned short* u2 = (const unsigned short*)&a2;
                const float w0 = wgt[tt][0], w1 = wgt[tt][1], w2 = wgt[tt][2];
#pragma unroll
                for (int e2i = 0; e2i < 4; ++e2i) {
                    float zl = w0 * bf2f(u0[e2i * 2]) + w1 * bf2f(u1[e2i * 2]) +
                               w2 * bf2f(u2[e2i * 2]);
                    float zh = w0 * bf2f(u0[e2i * 2 + 1]) + w1 * bf2f(u1[e2i * 2 + 1]) +
                               w2 * bf2f(u2[e2i * 2 + 1]);
                    asm("v_cvt_pk_bf16_f32 %0, %1, %2"
                        : "=v"(za[tt].w[e2i]) : "v"(zl), "v"(zh));
                }
            }
            __builtin_amdgcn_s_setprio(1);
#pragma unroll
            for (int ch = 0; ch < 2; ++ch)
#pragma unroll
                for (int cfl = 0; cfl < 4; ++cfl) {
                    bf16x8 b = *(const bf16x8*)(bp + (ch * 2 + cg) * 2048 +
                                    ((cfl * 16 + r16) * 4 + fragsw) * 8);
#pragma unroll
                    for (int tt = 0; tt < 2; ++tt)
                        oacc[tt * 8 + ch * 4 + cfl] =
                            __builtin_amdgcn_mfma_f32_16x16x32_bf16(
                                za[tt].v, b, oacc[tt * 8 + ch * 4 + cfl], 0, 0, 0);
                }
            __builtin_amdgcn_s_setprio(0);
        }
    }

    // ================= Epilogue: out = oacc + bias =================
#pragma unroll
    for (int tt = 0; tt < 2; ++tt)
#pragma unroll
        for (int cf = 0; cf < 8; ++cf) {
            const int gc = (cf >> 2) * 128 + cg * 64 + (cf & 3) * 16 + r16;
            float bc = bias[gc];
            f32x4 v = oacc[tt * 8 + cf];
#pragma unroll
            for (int r = 0; r < 4; ++r)
                out[(size_t)(t0 + tokb + tt * 16 + q * 4 + r) * CC + gc] = v[r] + bc;
        }
}

// ---------------------------------------------------------------------------
extern "C" void kernel_launch(void* const* d_in, const int* in_sizes, int n_in,
                              void* d_out, int out_size, void* d_ws, size_t ws_size,
                              hipStream_t stream) {
    const float* x = (const float*)d_in[0];      // (16, 4096, 256)
    const float* Wqkv = (const float*)d_in[1];   // (3, 256, 768)
    const float* Wproj = (const float*)d_in[2];  // (256, 256)
    const float* bproj = (const float*)d_in[3];  // (256,)
    float* out = (float*)d_out;                  // (16, 4096, 256)

    unsigned short* MtY = (unsigned short*)d_ws;           // (768,256): [(i,b)][a]
    unsigned short* PtZ = MtY + (size_t)NC * CC;           // (256,768): [g][(i,a)]

    prep<<<dim3(6, 2, 4), 256, 0, stream>>>(Wqkv, Wproj, MtY, PtZ);
    mega<<<MTOT / 64, 256, 0, stream>>>(x, MtY, PtZ, bproj, out);
}

// Round 10
// 204.001 us; speedup vs baseline: 1.9754x; 1.9754x over previous
//
#include <hip/hip_runtime.h>
#include <hip/hip_bf16.h>
#include <math.h>

// Problem constants
#define BB 16
#define NN 4096
#define CC 256
#define NC 768     // 3*C
#define MTOT (BB * NN)   // 65536 tokens

typedef __attribute__((ext_vector_type(8))) __bf16 bf16x8;
typedef __attribute__((ext_vector_type(4))) float f32x4;

__device__ __forceinline__ unsigned short f2bf(float f) {
    union { float f; unsigned int u; } v; v.f = f;
    unsigned int r = (v.u + 0x7FFFu + ((v.u >> 16) & 1u)) >> 16;
    return (unsigned short)r;
}
__device__ __forceinline__ float bf2f(unsigned short b) {
    union { unsigned int u; float f; } v; v.u = ((unsigned int)b) << 16;
    return v.f;
}

#define GL16(gp, lp) \
    __builtin_amdgcn_global_load_lds((const __attribute__((address_space(1))) void*)(gp), \
                                     (__attribute__((address_space(3))) void*)(lp), 16, 0, 0)

// ---------------------------------------------------------------------------
// PREP kernel: fuses the old conv_all (f32->bf16 repack) into the weight
// GEMMs (validated in the v5 run: passed, absmax unchanged).
//   z<3 : MtY_z = scale * Wk_z Wq_z^T  (256x256)
//   z=3 : PtZ = (1/3) * Wproj^T x Wv   (256x768)
// ---------------------------------------------------------------------------
__global__ __launch_bounds__(256) void prep(const float* __restrict__ Wqkv,
                                            const float* __restrict__ Wproj,
                                            unsigned short* __restrict__ MtY,
                                            unsigned short* __restrict__ PtZ) {
    const int z = blockIdx.z;
    if (z < 3 && blockIdx.x >= 2) return;
    const int bm = blockIdx.y * 128, bn = blockIdx.x * 128;
    const int nout = (z < 3) ? CC : NC;
    const float mult = (z < 3) ? 0.0625f : (1.0f / 3.0f);
    unsigned short* C = (z < 3) ? (MtY + (size_t)z * CC * CC) : PtZ;

    __shared__ unsigned short As[128 * 32];
    __shared__ unsigned short Bs[128 * 32];

    const int tid = threadIdx.x;
    const int lane = tid & 63;
    const int wave = tid >> 6;
    const int q = lane >> 4;
    const int r16 = lane & 15;
    const int wm = (wave >> 1) * 64;
    const int wn = (wave & 1) * 64;
    const int sw = (q ^ ((r16 >> 1) & 3)) * 8;

    const int r0 = tid >> 2, kc0 = (tid & 3) ^ ((r0 >> 1) & 3);
    const int e1 = tid + 256, r1 = e1 >> 2, kc1 = ((e1 & 3)) ^ ((r1 >> 1) & 3);

    f32x4 acc[4][4];
#pragma unroll
    for (int i = 0; i < 4; ++i)
#pragma unroll
        for (int j = 0; j < 4; ++j) acc[i][j] = {0.f, 0.f, 0.f, 0.f};

    for (int kt = 0; kt < CC; kt += 32) {
        if (kt) __syncthreads();
        // ---- stage A slots (e0,e1) and B slots (e0,e1): f32 -> bf16 -> LDS
        {
            float v[8];
            unsigned short p8[8];
            // A e0
            if (z < 3) {
                const float* p = Wqkv + (size_t)(z * 256 + bm + r0) * NC + 256 + kt + kc0 * 8;
                float4 a = *(const float4*)p, b = *(const float4*)(p + 4);
                v[0]=a.x; v[1]=a.y; v[2]=a.z; v[3]=a.w; v[4]=b.x; v[5]=b.y; v[6]=b.z; v[7]=b.w;
            } else {
                const float* p = Wproj + (size_t)(kt + kc0 * 8) * CC + bm + r0;
#pragma unroll
                for (int j = 0; j < 8; ++j) v[j] = p[(size_t)j * CC];
            }
#pragma unroll
            for (int j = 0; j < 8; ++j) p8[j] = f2bf(v[j]);
            *(float4*)(As + tid * 8) = *(const float4*)p8;
            // A e1
            if (z < 3) {
                const float* p = Wqkv + (size_t)(z * 256 + bm + r1) * NC + 256 + kt + kc1 * 8;
                float4 a = *(const float4*)p, b = *(const float4*)(p + 4);
                v[0]=a.x; v[1]=a.y; v[2]=a.z; v[3]=a.w; v[4]=b.x; v[5]=b.y; v[6]=b.z; v[7]=b.w;
            } else {
                const float* p = Wproj + (size_t)(kt + kc1 * 8) * CC + bm + r1;
#pragma unroll
                for (int j = 0; j < 8; ++j) v[j] = p[(size_t)j * CC];
            }
#pragma unroll
            for (int j = 0; j < 8; ++j) p8[j] = f2bf(v[j]);
            *(float4*)(As + e1 * 8) = *(const float4*)p8;
            // B e0
            {
                const float* p = (z < 3)
                    ? Wqkv + (size_t)(z * 256 + bn + r0) * NC + kt + kc0 * 8
                    : Wqkv + (size_t)(bn + r0) * NC + 512 + kt + kc0 * 8;
                float4 a = *(const float4*)p, b = *(const float4*)(p + 4);
                p8[0]=f2bf(a.x); p8[1]=f2bf(a.y); p8[2]=f2bf(a.z); p8[3]=f2bf(a.w);
                p8[4]=f2bf(b.x); p8[5]=f2bf(b.y); p8[6]=f2bf(b.z); p8[7]=f2bf(b.w);
                *(float4*)(Bs + tid * 8) = *(const float4*)p8;
            }
            // B e1
            {
                const float* p = (z < 3)
                    ? Wqkv + (size_t)(z * 256 + bn + r1) * NC + kt + kc1 * 8
                    : Wqkv + (size_t)(bn + r1) * NC + 512 + kt + kc1 * 8;
                float4 a = *(const float4*)p, b = *(const float4*)(p + 4);
                p8[0]=f2bf(a.x); p8[1]=f2bf(a.y); p8[2]=f2bf(a.z); p8[3]=f2bf(a.w);
                p8[4]=f2bf(b.x); p8[5]=f2bf(b.y); p8[6]=f2bf(b.z); p8[7]=f2bf(b.w);
                *(float4*)(Bs + e1 * 8) = *(const float4*)p8;
            }
        }
        __syncthreads();

        bf16x8 afv[4], bfv[4];
#pragma unroll
        for (int mi = 0; mi < 4; ++mi)
            afv[mi] = *(const bf16x8*)(As + (wm + mi * 16 + r16) * 32 + sw);
#pragma unroll
        for (int ni = 0; ni < 4; ++ni)
            bfv[ni] = *(const bf16x8*)(Bs + (wn + ni * 16 + r16) * 32 + sw);
#pragma unroll
        for (int mi = 0; mi < 4; ++mi)
#pragma unroll
            for (int ni = 0; ni < 4; ++ni)
                acc[mi][ni] = __builtin_amdgcn_mfma_f32_16x16x32_bf16(
                    afv[mi], bfv[ni], acc[mi][ni], 0, 0, 0);
    }

#pragma unroll
    for (int mi = 0; mi < 4; ++mi)
#pragma unroll
        for (int ni = 0; ni < 4; ++ni) {
            int row0 = bm + wm + mi * 16 + q * 4;
            int col = bn + wn + ni * 16 + r16;
#pragma unroll
            for (int r = 0; r < 4; ++r)
                C[(size_t)(row0 + r) * nout + col] = f2bf(acc[mi][ni][r] * mult);
        }
}

// ---------------------------------------------------------------------------
// MEGA kernel, v4 verbatim (measured 114 us, VGPR 128, no spill):
// 2x2 wave split + 16KB super-stages (ring 2, 48 barriers).
//
// Waves = (tg, cg): tg = token group (32 tokens), cg = column group.
// Every stage engages ALL 4 waves (v3 lesson); every weight byte read by
// exactly 2 waves.  af[16] persistent (64 VGPR) — af[32] spills (v5 lesson).
//
// LDS: xbuf 70x264 (36960) + bstage 2x16KB (32768) + yseg 4x16x72 (9216)
//      + part 2x64x3 f32 (1536) = 80480 B -> 2 blocks/CU.
// ---------------------------------------------------------------------------
__global__ __launch_bounds__(256, 2) void mega(const float* __restrict__ xf,
                                               const unsigned short* __restrict__ MtY,
                                               const unsigned short* __restrict__ PtZ,
                                               const float* __restrict__ bias,
                                               float* __restrict__ out) {
    __shared__ __align__(16) unsigned short xbuf[70 * 264];
    __shared__ __align__(16) unsigned short bstage[2 * 8192];
    __shared__ __align__(16) unsigned short yseg[4 * 16 * 72];
    __shared__ __align__(16) float part[2][64][3];

    const int tid = threadIdx.x;
    const int lane = tid & 63;
    const int wv = tid >> 6;
    const int q = lane >> 4;
    const int r16 = lane & 15;
    const int tg = wv >> 1;        // token group (32 tokens)
    const int cg = wv & 1;         // column group (interleaved 64-col chunks)
    const int t0 = blockIdx.x * 64;
    const int tokb = tg * 32;

    // staging source precompute (conflict swizzle: slot (tid&3) holds kc)
    const int c2t = tid >> 2;                       // 0..63
    const int kct = (tid & 3) ^ ((tid >> 3) & 3);
    const unsigned short* mB = MtY + (size_t)c2t * CC + kct * 8;
    const unsigned short* pB = PtZ + (size_t)c2t * NC + kct * 8;

    // Stage gs (0..47): dil i2 = gs>>4; r = gs&15.
    auto issue_stage = [&](int gs) {
        if (gs >= 48) return;
        unsigned short* dst = bstage + (gs & 1) * 8192 + tid * 8;
        const int i2 = gs >> 4;
        const int r = gs & 15;
        if (r < 8) {   // M: 128 cols (ch half) x 64 k
            const unsigned short* s0 =
                mB + (size_t)(i2 * 256 + (r >> 2) * 128) * CC + (r & 3) * 64;
            GL16(s0, dst);                                  // khalf0, cols 0..63
            GL16(s0 + (size_t)64 * CC, dst + 2048);         // khalf0, cols 64..127
            GL16(s0 + 32, dst + 4096);                      // khalf1, cols 0..63
            GL16(s0 + (size_t)64 * CC + 32, dst + 6144);    // khalf1, cols 64..127
        } else {       // P: 256 g x 32 a (kt = r-8)
            const unsigned short* s0 = pB + i2 * 256 + (r - 8) * 32;
            GL16(s0, dst);                                  // g 0..63
            GL16(s0 + (size_t)64 * NC, dst + 2048);         // g 64..127
            GL16(s0 + (size_t)128 * NC, dst + 4096);        // g 128..191
            GL16(s0 + (size_t)192 * NC, dst + 6144);        // g 192..255
        }
    };

    issue_stage(0);   // flies while x is staged

    // ---- stage x rows [t0-3, t0+67) fp32 -> bf16 LDS (clamped; masked later)
    for (int it = 0; it < 9; ++it) {
        int e = it * 256 + tid;          // 70 rows * 32 chunks = 2240
        if (e < 2240) {
            int rr = e >> 5, c = e & 31;
            int gr = t0 - 3 + rr;
            gr = gr < 0 ? 0 : (gr > MTOT - 1 ? MTOT - 1 : gr);
            const float* xp = xf + (size_t)gr * CC + c * 8;
            float4 a = *(const float4*)xp;
            float4 b = *(const float4*)(xp + 4);
            unsigned short p[8];
            p[0] = f2bf(a.x); p[1] = f2bf(a.y); p[2] = f2bf(a.z); p[3] = f2bf(a.w);
            p[4] = f2bf(b.x); p[5] = f2bf(b.y); p[6] = f2bf(b.z); p[7] = f2bf(b.w);
            *(float4*)(xbuf + rr * 264 + c * 8) = *(const float4*)p;
        }
    }
    __syncthreads();   // drains x loads AND stage 0 (one-time vmcnt(0))

    // persistent A-fragments: wave's 32 tokens x 256 k (2 tf x 8 kt)
    bf16x8 af[16];
#pragma unroll
    for (int tf = 0; tf < 2; ++tf)
#pragma unroll
        for (int kt = 0; kt < 8; ++kt)
            af[tf * 8 + kt] = *(const bf16x8*)(xbuf + (3 + tokb + tf * 16 + r16) * 264 +
                                               kt * 32 + q * 8);

    f32x4 oacc[16];   // [tf*8 + cf]: rows tokb+tf*16+q*4+r, col (cf>>2)*128+cg*64+(cf&3)*16+r16
#pragma unroll
    for (int j = 0; j < 16; ++j) oacc[j] = {0.f, 0.f, 0.f, 0.f};

    const int fragsw = q ^ ((r16 >> 1) & 3);   // fragment k-chunk swizzle

#pragma unroll 1
    for (int i = 0; i < 3; ++i) {
        const int dil = i + 1;
        f32x4 yacc[8];    // current ch-half: [tf*4 + cfl]
#pragma unroll
        for (int j = 0; j < 8; ++j) yacc[j] = {0.f, 0.f, 0.f, 0.f};
        float dg[2][3];   // logit partial accumulator (diag lanes)
        float wgt[2][3];  // softmax weights
        union ZA { unsigned int w[4]; bf16x8 v; };
        ZA za[2];

        // ================= M phase: 8 slots (ch-major) =================
#pragma unroll
        for (int sl = 0; sl < 8; ++sl) {
            asm volatile("s_waitcnt vmcnt(0)" ::: "memory");  // stage ready (this wave)
            __builtin_amdgcn_s_barrier();                     // -> ready block-wide
            __builtin_amdgcn_sched_barrier(0);
            const unsigned short* bp = bstage + (sl & 1) * 8192;
            issue_stage(i * 16 + sl + 1);
#pragma unroll
            for (int h = 0; h < 2; ++h) {     // two 32-k halves of the stage
                bf16x8 bfr[4];
#pragma unroll
                for (int cfl = 0; cfl < 4; ++cfl)
                    bfr[cfl] = *(const bf16x8*)(bp + h * 4096 +
                                   ((cg * 64 + cfl * 16 + r16) * 4 + fragsw) * 8);
                __builtin_amdgcn_s_setprio(1);
#pragma unroll
                for (int tf = 0; tf < 2; ++tf)
#pragma unroll
                    for (int cfl = 0; cfl < 4; ++cfl)
                        yacc[tf * 4 + cfl] = __builtin_amdgcn_mfma_f32_16x16x32_bf16(
                            af[tf * 8 + (sl & 3) * 2 + h], bfr[cfl],
                            yacc[tf * 4 + cfl], 0, 0, 0);
                __builtin_amdgcn_s_setprio(0);
            }
            // logit pass when a ch-half completes (sl==3: ch0, sl==7: ch1)
            if (sl == 3 || sl == 7) {
                const int hh = sl >> 2;
                unsigned short* ys = yseg + wv * (16 * 72);
#pragma unroll
                for (int tf = 0; tf < 2; ++tf) {
#pragma unroll
                    for (int cfl = 0; cfl < 4; ++cfl)
#pragma unroll
                        for (int rr = 0; rr < 4; ++rr)
                            ys[(q * 4 + rr) * 72 + cfl * 16 + r16] =
                                f2bf(yacc[tf * 4 + cfl][rr]);
                    asm volatile("s_waitcnt lgkmcnt(0)" ::: "memory");
                    __builtin_amdgcn_sched_barrier(0);
                    bf16x8 ya0 = *(const bf16x8*)(ys + r16 * 72 + q * 8);
                    bf16x8 ya1 = *(const bf16x8*)(ys + r16 * 72 + 32 + q * 8);
                    f32x4 lc[3];
#pragma unroll
                    for (int j = 0; j < 3; ++j) lc[j] = {0.f, 0.f, 0.f, 0.f};
#pragma unroll
                    for (int j = 0; j < 3; ++j) {
                        const unsigned short* xr =
                            xbuf + (3 + tokb + tf * 16 + r16 + (j - 1) * dil) * 264 +
                            hh * 128 + cg * 64 + q * 8;
                        lc[j] = __builtin_amdgcn_mfma_f32_16x16x32_bf16(
                            ya0, *(const bf16x8*)xr, lc[j], 0, 0, 0);
                        lc[j] = __builtin_amdgcn_mfma_f32_16x16x32_bf16(
                            ya1, *(const bf16x8*)(xr + 32), lc[j], 0, 0, 0);
                    }
                    if (q == (r16 >> 2)) {     // diag lanes own token tokb+tf*16+r16
                        const int rs = r16 & 3;
#pragma unroll
                        for (int j = 0; j < 3; ++j) {
                            float v = rs == 0 ? lc[j][0] : rs == 1 ? lc[j][1]
                                    : rs == 2 ? lc[j][2] : lc[j][3];
                            dg[tf][j] = hh == 0 ? v : dg[tf][j] + v;
                        }
                    }
                }
                if (hh == 0) {
#pragma unroll
                    for (int j = 0; j < 8; ++j) yacc[j] = {0.f, 0.f, 0.f, 0.f};
                } else {
                    if (q == (r16 >> 2)) {
#pragma unroll
                        for (int tf = 0; tf < 2; ++tf) {
                            float* pp = &part[cg][tokb + tf * 16 + r16][0];
                            pp[0] = dg[tf][0]; pp[1] = dg[tf][1]; pp[2] = dg[tf][2];
                        }
                    }
                    asm volatile("s_waitcnt lgkmcnt(0)" ::: "memory");
                }
            }
        }

        // ================= P phase: 8 slots (kt 0..7) =================
#pragma unroll
        for (int sl = 0; sl < 8; ++sl) {
            asm volatile("s_waitcnt vmcnt(0)" ::: "memory");
            __builtin_amdgcn_s_barrier();
            __builtin_amdgcn_sched_barrier(0);
            const unsigned short* bp = bstage + (sl & 1) * 8192;
            issue_stage(i * 16 + 8 + sl + 1);
            if (sl == 0) {
                // combine cg partials + softmax (replicated; all lanes)
#pragma unroll
                for (int tf = 0; tf < 2; ++tf) {
                    const int tok = tokb + tf * 16 + r16;
                    float l0 = part[0][tok][0] + part[1][tok][0];
                    float l1 = part[0][tok][1] + part[1][tok][1];
                    float l2 = part[0][tok][2] + part[1][tok][2];
                    const int ns = (t0 + tok) & (NN - 1);
                    const bool vlo = ns >= dil;
                    const bool vhi = ns + dil < NN;
                    l0 = vlo ? l0 : 0.f;    // zero-logit padding (matches reference)
                    l2 = vhi ? l2 : 0.f;
                    float mx = fmaxf(l0, fmaxf(l1, l2));
                    float e0 = __expf(l0 - mx), e1 = __expf(l1 - mx), e2 = __expf(l2 - mx);
                    float inv = 1.0f / (e0 + e1 + e2);
                    wgt[tf][0] = vlo ? e0 * inv : 0.f;
                    wgt[tf][1] = e1 * inv;
                    wgt[tf][2] = vhi ? e2 * inv : 0.f;
                }
            }
            // build z A-frags for this k-chunk (center term from persistent af)
#pragma unroll
            for (int tf = 0; tf < 2; ++tf) {
                const unsigned short* xr1 =
                    xbuf + (3 + tokb + tf * 16 + r16) * 264 + sl * 32 + q * 8;
                bf16x8 a0 = *(const bf16x8*)(xr1 - dil * 264);
                bf16x8 a2 = *(const bf16x8*)(xr1 + dil * 264);
                const unsigned short* u0 = (const unsigned short*)&a0;
                const unsigned short* u1 = (const unsigned short*)&af[tf * 8 + sl];
                const unsigned short* u2 = (const unsigned short*)&a2;
                const float w0 = wgt[tf][0], w1 = wgt[tf][1], w2 = wgt[tf][2];
#pragma unroll
                for (int e2i = 0; e2i < 4; ++e2i) {
                    float zl = w0 * bf2f(u0[e2i * 2]) + w1 * bf2f(u1[e2i * 2]) +
                               w2 * bf2f(u2[e2i * 2]);
                    float zh = w0 * bf2f(u0[e2i * 2 + 1]) + w1 * bf2f(u1[e2i * 2 + 1]) +
                               w2 * bf2f(u2[e2i * 2 + 1]);
                    asm("v_cvt_pk_bf16_f32 %0, %1, %2"
                        : "=v"(za[tf].w[e2i]) : "v"(zl), "v"(zh));
                }
            }
            __builtin_amdgcn_s_setprio(1);
#pragma unroll
            for (int ch = 0; ch < 2; ++ch)
#pragma unroll
                for (int cfl = 0; cfl < 4; ++cfl) {
                    bf16x8 b = *(const bf16x8*)(bp + (ch * 2 + cg) * 2048 +
                                    ((cfl * 16 + r16) * 4 + fragsw) * 8);
#pragma unroll
                    for (int tf = 0; tf < 2; ++tf)
                        oacc[tf * 8 + ch * 4 + cfl] =
                            __builtin_amdgcn_mfma_f32_16x16x32_bf16(
                                za[tf].v, b, oacc[tf * 8 + ch * 4 + cfl], 0, 0, 0);
                }
            __builtin_amdgcn_s_setprio(0);
        }
    }

    // ================= Epilogue: out = oacc + bias =================
#pragma unroll
    for (int tf = 0; tf < 2; ++tf)
#pragma unroll
        for (int cf = 0; cf < 8; ++cf) {
            const int gc = (cf >> 2) * 128 + cg * 64 + (cf & 3) * 16 + r16;
            float bc = bias[gc];
            f32x4 v = oacc[tf * 8 + cf];
#pragma unroll
            for (int r = 0; r < 4; ++r)
                out[(size_t)(t0 + tokb + tf * 16 + q * 4 + r) * CC + gc] = v[r] + bc;
        }
}

// ---------------------------------------------------------------------------
extern "C" void kernel_launch(void* const* d_in, const int* in_sizes, int n_in,
                              void* d_out, int out_size, void* d_ws, size_t ws_size,
                              hipStream_t stream) {
    const float* x = (const float*)d_in[0];      // (16, 4096, 256)
    const float* Wqkv = (const float*)d_in[1];   // (3, 256, 768)
    const float* Wproj = (const float*)d_in[2];  // (256, 256)
    const float* bproj = (const float*)d_in[3];  // (256,)
    float* out = (float*)d_out;                  // (16, 4096, 256)

    unsigned short* MtY = (unsigned short*)d_ws;           // (768,256): [(i,b)][a]
    unsigned short* PtZ = MtY + (size_t)NC * CC;           // (256,768): [g][(i,a)]

    prep<<<dim3(6, 2, 4), 256, 0, stream>>>(Wqkv, Wproj, MtY, PtZ);
    mega<<<MTOT / 64, 256, 0, stream>>>(x, MtY, PtZ, bproj, out);
}